// Round 14
// baseline (436.403 us; speedup 1.0000x reference)
//
#include <hip/hip_runtime.h>
#include <hip/hip_bf16.h>
#include <stdint.h>

// B=32, S=4096, ENC=512, DEC=512
// out = softmax_s( sum_d tanh( enc @ W_e^T + dh @ W_h^T + b ) * v )

typedef __attribute__((ext_vector_type(8))) short short8;
typedef __attribute__((ext_vector_type(4))) float f32x4;

static __device__ __forceinline__ short8 cvt8(float4 a, float4 b) {
    // 4x v_cvt_pk_bf16_f32 (RNE)
    union { short8 s; __hip_bfloat162 h[4]; } u;
    u.h[0] = __float22bfloat162_rn(float2{a.x, a.y});
    u.h[1] = __float22bfloat162_rn(float2{a.z, a.w});
    u.h[2] = __float22bfloat162_rn(float2{b.x, b.y});
    u.h[3] = __float22bfloat162_rn(float2{b.z, b.w});
    return u.s;
}

static __device__ __forceinline__ float tanh_fast(float x) {
    // tanh(x) = 1 - 2/(exp(2x)+1); overflow->+1, underflow->-1 (both correct)
    return 1.0f - 2.0f / (__expf(2.0f * x) + 1.0f);
}

// ---------------------------------------------------------------------------
// Kernel 1 (96 blocks x 512):
//   blocks 0..63 : W_e (= W_attn[:,512:]) -> bf16 into wsB, layout
//     [kt(16)][ks(4)][n(512)] x 16B: chunk (kt,ks,n) = W_e[n][kt*32+ks*8..+8].
//     A wave's B-frag read (fixed ni, llo=0..15) is 16 consecutive chunks
//     = 256B contiguous -> well-coalesced L2 reads in the fused kernel.
//   blocks 64..95: proj1[b][e] = sum_d dh[b,d]*W_attn[e,d] + b_attn[e]
// ---------------------------------------------------------------------------
__global__ __launch_bounds__(512) void prep_kernel(
    const float* __restrict__ dh, const float* __restrict__ W_attn,
    const float* __restrict__ b_attn, unsigned short* __restrict__ wsB,
    float* __restrict__ wsP1) {
    __shared__ float dhs[512];
    const int tid = threadIdx.x;
    if (blockIdx.x < 64) {
        int idx = blockIdx.x * 512 + tid;       // 0..32767 16B-chunks
        int n  = idx & 511;                     // W_e row (output dim d)
        int r  = idx >> 9;                      // 0..63
        int ks = r & 3;                         // 8-elem k-slot in 32-k tile
        int kt = r >> 2;                        // K tile 0..15
        const float* src = W_attn + (size_t)n * 1024 + 512 + kt * 32 + ks * 8;
        float4 f0 = *(const float4*)(src);
        float4 f1 = *(const float4*)(src + 4);
        *(short8*)((char*)wsB + (size_t)idx * 16) = cvt8(f0, f1);
    } else {
        int b = blockIdx.x - 64;
        dhs[tid] = dh[b * 512 + tid];
        __syncthreads();
        const float* wrow = W_attn + (size_t)tid * 1024;  // W_h row e=tid
        float acc = 0.f;
        #pragma unroll 8
        for (int d = 0; d < 512; d += 4) {
            float4 w = *(const float4*)(wrow + d);
            acc += dhs[d] * w.x + dhs[d + 1] * w.y + dhs[d + 2] * w.z + dhs[d + 3] * w.w;
        }
        wsP1[b * 512 + tid] = acc + b_attn[tid];
    }
}

// ---------------------------------------------------------------------------
// Kernel 2: fused GEMM (64 rows x 256 cols per block, K=512) + tanh + v-dot.
// 256 thr = 4 waves 1Mx4N; wave tile 64x64 = 4x4 frags of 16x16x32 bf16.
// ZERO barriers and ZERO LDS in the K-loop:
//   - A: direct global->reg (4 waves read the same 8KB kt-tile; L1 serves
//     the duplicates; HBM reads enc once). f32->bf16 via cvt_pk in-reg.
//   - B: direct global->reg from L2-resident wsB (512 KB, [kt][ks][n] layout
//     -> 4x256B contiguous per wave-frag-read).
// Software pipeline: next kt's A(f32) + B(short8) loads issued before this
// kt's 16 MFMAs; statically-named double-buffer reg sets (no dyn indexing).
// ~156 live regs -> launch_bounds(256,3): 3 blocks/CU = 12 free-running
// waves/CU (m114 regime, no convoy).
// cb=0 writes partial scores to out, cb=1 to wsS1; softmax adds them.
// ---------------------------------------------------------------------------
__global__ __launch_bounds__(256, 3) void fused_kernel(
    const float* __restrict__ enc, const unsigned short* __restrict__ wsB,
    const float* __restrict__ wsP1, const float* __restrict__ vvec,
    float* __restrict__ out, float* __restrict__ wsS1) {
    __shared__ float red[256];                   // [4 wc][64 rows], epilogue only

    const int tid  = threadIdx.x;
    const int wc   = tid >> 6;                    // wave = N-block 0..3
    const int lane = tid & 63;
    const int llo  = lane & 15, lhi = lane >> 4;

    // XCD-chunked bijective swizzle (4096 % 8 == 0); (rb, cb=0/1) partners
    // are adjacent logical blocks -> same XCD -> enc + wsB L2-hot.
    const int bid = blockIdx.x;
    const int lb  = (bid & 7) * 512 + (bid >> 3);
    const int rb  = lb >> 1, cb = lb & 1;
    const int m0  = rb * 64;
    const int b   = m0 >> 12;                     // batch (64 | 4096)

    // A-direct: lane (llo,lhi), frag mi, tile kt reads
    // enc[m0 + mi*16 + llo][kt*32 + lhi*8 .. +8]   (2 x float4)
    const float* abase = enc + (size_t)(m0 + llo) * 512 + lhi * 8;

    // B-direct: frag ni at kt reads wsB chunk (kt, lhi, cb*256+wc*64+ni*16+llo)
    // byte addr = kt*32768 + lhi*8192 + n*16
    const char* bbase = (const char*)wsB + lhi * 8192 +
                        (size_t)(cb * 256 + wc * 64 + llo) * 16;

    f32x4 acc[4][4] = {};
    float4 t0, t1, t2, t3, t4, t5, t6, t7;
    short8 afA0, afA1, afA2, afA3, afB0, afB1, afB2, afB3;
    short8 bfA0, bfA1, bfA2, bfA3, bfB0, bfB1, bfB2, bfB3;

    #define ALOADT(kt)                                                    \
        do { const float* p_ = abase + (kt) * 32;                         \
             t0 = *(const float4*)(p_);         t1 = *(const float4*)(p_ + 4);         \
             t2 = *(const float4*)(p_ + 8192);  t3 = *(const float4*)(p_ + 8196);      \
             t4 = *(const float4*)(p_ + 16384); t5 = *(const float4*)(p_ + 16388);     \
             t6 = *(const float4*)(p_ + 24576); t7 = *(const float4*)(p_ + 24580); } while (0)

    #define BLOADS(kt, B0, B1, B2, B3)                                    \
        do { const char* p_ = bbase + (size_t)(kt) * 32768;               \
             B0 = *(const short8*)(p_);       B1 = *(const short8*)(p_ + 256);  \
             B2 = *(const short8*)(p_ + 512); B3 = *(const short8*)(p_ + 768); } while (0)

    #define CVTA(A0, A1, A2, A3)                                          \
        do { A0 = cvt8(t0, t1); A1 = cvt8(t2, t3);                        \
             A2 = cvt8(t4, t5); A3 = cvt8(t6, t7); } while (0)

    #define MFMA16(A0, A1, A2, A3, B0, B1, B2, B3)                                     \
        do {                                                                            \
            acc[0][0] = __builtin_amdgcn_mfma_f32_16x16x32_bf16(A0, B0, acc[0][0], 0, 0, 0); \
            acc[0][1] = __builtin_amdgcn_mfma_f32_16x16x32_bf16(A0, B1, acc[0][1], 0, 0, 0); \
            acc[0][2] = __builtin_amdgcn_mfma_f32_16x16x32_bf16(A0, B2, acc[0][2], 0, 0, 0); \
            acc[0][3] = __builtin_amdgcn_mfma_f32_16x16x32_bf16(A0, B3, acc[0][3], 0, 0, 0); \
            acc[1][0] = __builtin_amdgcn_mfma_f32_16x16x32_bf16(A1, B0, acc[1][0], 0, 0, 0); \
            acc[1][1] = __builtin_amdgcn_mfma_f32_16x16x32_bf16(A1, B1, acc[1][1], 0, 0, 0); \
            acc[1][2] = __builtin_amdgcn_mfma_f32_16x16x32_bf16(A1, B2, acc[1][2], 0, 0, 0); \
            acc[1][3] = __builtin_amdgcn_mfma_f32_16x16x32_bf16(A1, B3, acc[1][3], 0, 0, 0); \
            acc[2][0] = __builtin_amdgcn_mfma_f32_16x16x32_bf16(A2, B0, acc[2][0], 0, 0, 0); \
            acc[2][1] = __builtin_amdgcn_mfma_f32_16x16x32_bf16(A2, B1, acc[2][1], 0, 0, 0); \
            acc[2][2] = __builtin_amdgcn_mfma_f32_16x16x32_bf16(A2, B2, acc[2][2], 0, 0, 0); \
            acc[2][3] = __builtin_amdgcn_mfma_f32_16x16x32_bf16(A2, B3, acc[2][3], 0, 0, 0); \
            acc[3][0] = __builtin_amdgcn_mfma_f32_16x16x32_bf16(A3, B0, acc[3][0], 0, 0, 0); \
            acc[3][1] = __builtin_amdgcn_mfma_f32_16x16x32_bf16(A3, B1, acc[3][1], 0, 0, 0); \
            acc[3][2] = __builtin_amdgcn_mfma_f32_16x16x32_bf16(A3, B2, acc[3][2], 0, 0, 0); \
            acc[3][3] = __builtin_amdgcn_mfma_f32_16x16x32_bf16(A3, B3, acc[3][3], 0, 0, 0); \
        } while (0)

    // ---- prologue: kt 0 into the A-set ----
    ALOADT(0);
    BLOADS(0, bfA0, bfA1, bfA2, bfA3);
    CVTA(afA0, afA1, afA2, afA3);

    // ---- barrier-free K-loop: 8 iterations x 2 kt, static reg rotation ----
    #pragma unroll 1
    for (int k2 = 0; k2 < 8; ++k2) {
        const int kt = k2 * 2;
        // body A (kt): prefetch kt+1, compute A-set
        ALOADT(kt + 1);
        BLOADS(kt + 1, bfB0, bfB1, bfB2, bfB3);
        MFMA16(afA0, afA1, afA2, afA3, bfA0, bfA1, bfA2, bfA3);
        CVTA(afB0, afB1, afB2, afB3);             // waits on t* (kt+1 A)
        // body B (kt+1): prefetch kt+2 (except last), compute B-set
        if (k2 < 7) {
            ALOADT(kt + 2);
            BLOADS(kt + 2, bfA0, bfA1, bfA2, bfA3);
        }
        MFMA16(afB0, afB1, afB2, afB3, bfB0, bfB1, bfB2, bfB3);
        if (k2 < 7) CVTA(afA0, afA1, afA2, afA3); // waits on t* (kt+2 A)
    }

    // --- epilogue: tanh(acc + proj1[b,d]) * v[d], partial-reduce over d ---
    float p1v[4], vv[4];
    #pragma unroll
    for (int ni = 0; ni < 4; ++ni) {
        int d = cb * 256 + wc * 64 + ni * 16 + llo;
        p1v[ni] = wsP1[b * 512 + d];
        vv[ni]  = vvec[d];
    }
    float part[16];
    #pragma unroll
    for (int mi = 0; mi < 4; ++mi)
        #pragma unroll
        for (int r = 0; r < 4; ++r) {
            float s = 0.f;
            #pragma unroll
            for (int ni = 0; ni < 4; ++ni)
                s += tanh_fast(acc[mi][ni][r] + p1v[ni]) * vv[ni];
            part[mi * 4 + r] = s;
        }
    // reduce across the 16-lane column group (lane bits 0..3)
    #pragma unroll
    for (int off = 1; off < 16; off <<= 1)
        #pragma unroll
        for (int i = 0; i < 16; ++i)
            part[i] += __shfl_xor(part[i], off, 64);

    if (llo == 0) {
        #pragma unroll
        for (int mi = 0; mi < 4; ++mi)
            #pragma unroll
            for (int r = 0; r < 4; ++r)
                red[wc * 64 + mi * 16 + lhi * 4 + r] = part[mi * 4 + r];
    }
    __syncthreads();
    if (tid < 64) {
        float s = red[tid] + red[64 + tid] + red[128 + tid] + red[192 + tid];
        (cb ? wsS1 : out)[m0 + tid] = s;
    }
}

// ---------------------------------------------------------------------------
// Kernel 3: add the two column-half partials, row softmax over S=4096,
// write to out. 32 blocks x 256.
// ---------------------------------------------------------------------------
__global__ __launch_bounds__(256) void softmax_kernel(
    float* __restrict__ out, const float* __restrict__ wsS1) {
    __shared__ float wred[8];
    const int b = blockIdx.x, tid = threadIdx.x;
    float* row = out + (size_t)b * 4096;
    const float* row1 = wsS1 + (size_t)b * 4096;
    float vals[16];
    float lmax = -1e30f;
    #pragma unroll
    for (int i = 0; i < 16; ++i) {
        vals[i] = row[i * 256 + tid] + row1[i * 256 + tid];
        lmax = fmaxf(lmax, vals[i]);
    }
    #pragma unroll
    for (int off = 32; off >= 1; off >>= 1)
        lmax = fmaxf(lmax, __shfl_xor(lmax, off, 64));
    if ((tid & 63) == 0) wred[tid >> 6] = lmax;
    __syncthreads();
    float gmax = fmaxf(fmaxf(wred[0], wred[1]), fmaxf(wred[2], wred[3]));
    float lsum = 0.f;
    #pragma unroll
    for (int i = 0; i < 16; ++i) {
        vals[i] = expf(vals[i] - gmax);
        lsum += vals[i];
    }
    #pragma unroll
    for (int off = 32; off >= 1; off >>= 1)
        lsum += __shfl_xor(lsum, off, 64);
    if ((tid & 63) == 0) wred[4 + (tid >> 6)] = lsum;
    __syncthreads();
    float inv = 1.f / (wred[4] + wred[5] + wred[6] + wred[7]);
    #pragma unroll
    for (int i = 0; i < 16; ++i)
        row[i * 256 + tid] = vals[i] * inv;
}

extern "C" void kernel_launch(void* const* d_in, const int* in_sizes, int n_in,
                              void* d_out, int out_size, void* d_ws, size_t ws_size,
                              hipStream_t stream) {
    const float* dh   = (const float*)d_in[0];   // (32, 512)
    const float* enc  = (const float*)d_in[1];   // (32, 4096, 512)
    const float* Wat  = (const float*)d_in[2];   // (512, 1024)
    const float* batt = (const float*)d_in[3];   // (512,)
    const float* vvec = (const float*)d_in[4];   // (512,)
    float* out = (float*)d_out;                  // (32, 4096)

    unsigned short* wsB = (unsigned short*)d_ws;               // 512 KB bf16 W_e
    float* wsP1 = (float*)((char*)d_ws + 524288);              // 64 KB proj1
    float* wsS1 = (float*)((char*)d_ws + 589824);              // 512 KB partial

    hipLaunchKernelGGL(prep_kernel, dim3(96), dim3(512), 0, stream,
                       dh, Wat, batt, wsB, wsP1);
    hipLaunchKernelGGL(fused_kernel, dim3(4096), dim3(256), 0, stream,
                       enc, wsB, wsP1, vvec, out, wsS1);
    hipLaunchKernelGGL(softmax_kernel, dim3(32), dim3(256), 0, stream, out, wsS1);
}

// Round 15
// 175.295 us; speedup vs baseline: 2.4895x; 2.4895x over previous
//
#include <hip/hip_runtime.h>
#include <hip/hip_bf16.h>
#include <stdint.h>

// B=32, S=4096, ENC=512, DEC=512
// out = softmax_s( sum_d tanh( enc @ W_e^T + dh @ W_h^T + b ) * v )

typedef __attribute__((ext_vector_type(8))) short short8;
typedef __attribute__((ext_vector_type(4))) float f32x4;

static __device__ __forceinline__ short8 cvt8(float4 a, float4 b) {
    // 4x v_cvt_pk_bf16_f32 (RNE)
    union { short8 s; __hip_bfloat162 h[4]; } u;
    u.h[0] = __float22bfloat162_rn(float2{a.x, a.y});
    u.h[1] = __float22bfloat162_rn(float2{a.z, a.w});
    u.h[2] = __float22bfloat162_rn(float2{b.x, b.y});
    u.h[3] = __float22bfloat162_rn(float2{b.z, b.w});
    return u.s;
}

static __device__ __forceinline__ float tanh_fast(float x) {
    // tanh(x) = 1 - 2/(exp(2x)+1); overflow->+1, underflow->-1 (both correct)
    return 1.0f - 2.0f / (__expf(2.0f * x) + 1.0f);
}

// ---------------------------------------------------------------------------
// Kernel 1 (96 blocks x 512):
//   blocks 0..63 : W_e (= W_attn[:,512:]) -> bf16 into wsB, layout
//     [cb(2)][t(8)][h(2)][row(128)][slot(8)] x 16B where chunk content =
//     W_e[cb*256 + h*128 + row][t*64 + (slot^(row&7))*8 .. +8]  (pre-swizzled
//     so the fused kernel global_load_lds's it LINEARLY and reads slot
//     (kk*4+lhi)^(row&7) conflict-free -- the R3/R8/R9-proven swizzle).
//   blocks 64..95: proj1[b][e] = sum_d dh[b,d]*W_attn[e,d] + b_attn[e]
// ---------------------------------------------------------------------------
__global__ __launch_bounds__(512) void prep_kernel(
    const float* __restrict__ dh, const float* __restrict__ W_attn,
    const float* __restrict__ b_attn, unsigned short* __restrict__ wsB,
    float* __restrict__ wsP1) {
    __shared__ float dhs[512];
    const int tid = threadIdx.x;
    if (blockIdx.x < 64) {
        int idx  = blockIdx.x * 512 + tid;      // 0..32767 16B-chunks
        int slot = idx & 7;
        int row  = (idx >> 3) & 127;
        int h    = (idx >> 10) & 1;
        int t    = (idx >> 11) & 7;
        int cbb  = (idx >> 14) & 1;
        int u    = slot ^ (row & 7);
        const float* src = W_attn + (size_t)(cbb * 256 + h * 128 + row) * 1024 +
                           512 + t * 64 + u * 8;
        float4 f0 = *(const float4*)(src);
        float4 f1 = *(const float4*)(src + 4);
        *(short8*)((char*)wsB + (size_t)idx * 16) = cvt8(f0, f1);
    } else {
        int b = blockIdx.x - 64;
        dhs[tid] = dh[b * 512 + tid];
        __syncthreads();
        const float* wrow = W_attn + (size_t)tid * 1024;  // W_h row e=tid
        float acc = 0.f;
        #pragma unroll 8
        for (int d = 0; d < 512; d += 4) {
            float4 w = *(const float4*)(wrow + d);
            acc += dhs[d] * w.x + dhs[d + 1] * w.y + dhs[d + 2] * w.z + dhs[d + 3] * w.w;
        }
        wsP1[b * 512 + tid] = acc + b_attn[tid];
    }
}

// ---------------------------------------------------------------------------
// Kernel 2: m201-style 8-phase fused GEMM. 256 rows x 256 cols per block,
// K=512 (8 K-tiles of BK=64). 512 thr = 8 waves (2M x 4N), wave out 128x64
// (acc[8][4]). LDS 128 KB: A[2 dbuf][2 half][128][64] bf16 + B same.
// Per K-tile = 4 phases; each phase: {ds_read frags | staging issue/write |
// bar | lgkm(0) | setprio(1) 16 MFMA setprio(0) | bar}. Counted vmcnt:
// A f32 loads (issued P0) land across 1-2 phases; B glds (issued P1) drain
// at P3's vmcnt(0) with 2 phases of cover. Never vmcnt(0) mid-tile.
// cb=0 writes partial scores to out, cb=1 to wsS1; softmax adds them.
// ---------------------------------------------------------------------------
__global__ __launch_bounds__(512, 2) void fused_kernel(
    const float* __restrict__ enc, const unsigned short* __restrict__ wsB,
    const float* __restrict__ wsP1, const float* __restrict__ vvec,
    float* __restrict__ out, float* __restrict__ wsS1) {
    __shared__ char lds[131072];   // A [0,64K): d*32768+h*16384; B [64K,128K)

    const int tid  = threadIdx.x;
    const int wave = tid >> 6;
    const int lane = tid & 63;
    const int llo  = lane & 15, lhi = lane >> 4;
    const int wr   = wave >> 2, wc = wave & 3;

    // XCD-chunked bijective swizzle (1024 % 8 == 0); cb-partners 8 apart
    // in blockIdx -> same XCD -> enc A-panel fetched once, shared via L2.
    const int bid = blockIdx.x;
    const int lb  = (bid & 7) * 128 + (bid >> 3);
    const int rb  = lb >> 1, cb = lb & 1;
    const int m0  = rb * 256;
    const int b   = m0 >> 12;                    // batch (256 | 4096)

    // fragment-read swizzled slot offsets (slot = (kk*4+lhi) ^ (llo&7))
    const int sw0 = ((lhi ^ (llo & 7)) << 4);
    const int sw1 = (((4 + lhi) ^ (llo & 7)) << 4);
    // B per-ni row base (row = output col local to cb-half)
    int bb[4];
    #pragma unroll
    for (int ni = 0; ni < 4; ++ni) {
        int row = wc * 64 + ni * 16 + llo;
        bb[ni] = (row >> 7) * 16384 + (row & 127) * 128;
    }
    // A staging map: thread -> (row ar in half, 16-f32 chunk ac)
    const int ar = tid >> 2, ac = tid & 3;
    const float* aBase = enc + (size_t)(m0 + ar) * 512 + ac * 16;
    const int swA0 = (((ac * 2)     ^ (ar & 7)) << 4);
    const int swA1 = (((ac * 2 + 1) ^ (ar & 7)) << 4);
    const int aWoff = ar * 128;
    const char* bSrc = (const char*)wsB + (size_t)cb * 262144;

    f32x4 acc[8][4] = {};
    float4 gA0, gA1, gA2, gA3, gB0, gB1, gB2, gB3;
    short8 af[4], bf[8];

    #define SCHEDB() __builtin_amdgcn_sched_barrier(0)
    #define BAR() __builtin_amdgcn_s_barrier()

    #define AISSUE(t1, h, G0, G1, G2, G3)                                 \
        do { const float* p_ = aBase + (h) * 65536 + (t1) * 64;           \
             G0 = *(const float4*)(p_);     G1 = *(const float4*)(p_ + 4); \
             G2 = *(const float4*)(p_ + 8); G3 = *(const float4*)(p_ + 12); } while (0)

    #define AWRITE(nd, h, G0, G1, G2, G3)                                 \
        do { char* w_ = lds + (nd) * 32768 + (h) * 16384 + aWoff;         \
             *(short8*)(w_ + swA0) = cvt8(G0, G1);                        \
             *(short8*)(w_ + swA1) = cvt8(G2, G3); } while (0)

    #define BGLDS(t1, nd)                                                             \
        do { const char* s_ = bSrc + (size_t)(t1) * 32768;                            \
             _Pragma("unroll")                                                        \
             for (int j_ = 0; j_ < 4; ++j_)                                           \
                 __builtin_amdgcn_global_load_lds(                                    \
                     (const uint32_t __attribute__((address_space(1)))*)(s_ + j_ * 8192 + tid * 16), \
                     (uint32_t __attribute__((address_space(3)))*)(lds + 65536 +      \
                         (nd) * 32768 + j_ * 8192 + tid * 16),                        \
                     16, 0, 0); } while (0)

    #define BFRAGS(d)                                                     \
        do { const char* B_ = lds + 65536 + (d) * 32768;                  \
             _Pragma("unroll")                                            \
             for (int ni_ = 0; ni_ < 4; ++ni_) {                          \
                 bf[ni_ * 2]     = *(const short8*)(B_ + bb[ni_] + sw0);  \
                 bf[ni_ * 2 + 1] = *(const short8*)(B_ + bb[ni_] + sw1); } } while (0)

    #define AFRAGS(d, q)                                                              \
        do { const char* A_ = lds + (d) * 32768 + wr * 16384;                         \
             af[0] = *(const short8*)(A_ + (((q) * 2    ) * 16 + llo) * 128 + sw0);   \
             af[1] = *(const short8*)(A_ + (((q) * 2    ) * 16 + llo) * 128 + sw1);   \
             af[2] = *(const short8*)(A_ + (((q) * 2 + 1) * 16 + llo) * 128 + sw0);   \
             af[3] = *(const short8*)(A_ + (((q) * 2 + 1) * 16 + llo) * 128 + sw1); } while (0)

    #define MFMAQ(q)                                                                  \
        do { _Pragma("unroll")                                                        \
             for (int ni_ = 0; ni_ < 4; ++ni_) {                                      \
                 acc[(q)*2  ][ni_] = __builtin_amdgcn_mfma_f32_16x16x32_bf16(af[0], bf[ni_*2  ], acc[(q)*2  ][ni_], 0, 0, 0); \
                 acc[(q)*2  ][ni_] = __builtin_amdgcn_mfma_f32_16x16x32_bf16(af[1], bf[ni_*2+1], acc[(q)*2  ][ni_], 0, 0, 0); \
                 acc[(q)*2+1][ni_] = __builtin_amdgcn_mfma_f32_16x16x32_bf16(af[2], bf[ni_*2  ], acc[(q)*2+1][ni_], 0, 0, 0); \
                 acc[(q)*2+1][ni_] = __builtin_amdgcn_mfma_f32_16x16x32_bf16(af[3], bf[ni_*2+1], acc[(q)*2+1][ni_], 0, 0, 0); } } while (0)

    // ---- prologue: stage K-tile 0 into dbuf 0 ----
    AISSUE(0, 0, gA0, gA1, gA2, gA3);                     // vm +4
    AISSUE(0, 1, gB0, gB1, gB2, gB3);                     // vm +4 -> 8
    BGLDS(0, 0);                                          // vm +4 -> 12
    asm volatile("s_waitcnt vmcnt(8)" ::: "memory"); SCHEDB();
    AWRITE(0, 0, gA0, gA1, gA2, gA3);
    asm volatile("s_waitcnt vmcnt(4)" ::: "memory"); SCHEDB();
    AWRITE(0, 1, gB0, gB1, gB2, gB3);
    asm volatile("s_waitcnt vmcnt(0) lgkmcnt(0)" ::: "memory");
    SCHEDB(); BAR(); SCHEDB();

    // ---- main loop: K-tiles 0..6, staging kt+1 into the other dbuf ----
    #pragma unroll 1
    for (int kt = 0; kt < 7; ++kt) {
        const int d = kt & 1, nd = d ^ 1, t1 = kt + 1;
        // P0: read B(8)+Aq0(4); issue both A halves of t1
        BFRAGS(d); AFRAGS(d, 0);
        AISSUE(t1, 0, gA0, gA1, gA2, gA3);                // vm 4
        AISSUE(t1, 1, gB0, gB1, gB2, gB3);                // vm 8
        SCHEDB(); BAR();
        asm volatile("s_waitcnt lgkmcnt(0)" ::: "memory"); SCHEDB();
        __builtin_amdgcn_s_setprio(1); MFMAQ(0); __builtin_amdgcn_s_setprio(0);
        SCHEDB(); BAR(); SCHEDB();
        // P1: read Aq1; vmcnt(4)->Ah0 landed; write Ah0; issue B glds
        AFRAGS(d, 1);
        asm volatile("s_waitcnt vmcnt(4)" ::: "memory"); SCHEDB();
        AWRITE(nd, 0, gA0, gA1, gA2, gA3);
        BGLDS(t1, nd);                                    // vm 8 (gB4 + glds4)
        SCHEDB(); BAR();
        asm volatile("s_waitcnt lgkmcnt(0)" ::: "memory"); SCHEDB();
        __builtin_amdgcn_s_setprio(1); MFMAQ(1); __builtin_amdgcn_s_setprio(0);
        SCHEDB(); BAR(); SCHEDB();
        // P2: read Aq2; vmcnt(4)->Ah1 landed (glds out); write Ah1
        AFRAGS(d, 2);
        asm volatile("s_waitcnt vmcnt(4)" ::: "memory"); SCHEDB();
        AWRITE(nd, 1, gB0, gB1, gB2, gB3);
        SCHEDB(); BAR();
        asm volatile("s_waitcnt lgkmcnt(0)" ::: "memory"); SCHEDB();
        __builtin_amdgcn_s_setprio(1); MFMAQ(2); __builtin_amdgcn_s_setprio(0);
        SCHEDB(); BAR(); SCHEDB();
        // P3: read Aq3; MFMA; then drain B glds (2 phases of cover) + publish
        AFRAGS(d, 3);
        SCHEDB(); BAR();
        asm volatile("s_waitcnt lgkmcnt(0)" ::: "memory"); SCHEDB();
        __builtin_amdgcn_s_setprio(1); MFMAQ(3); __builtin_amdgcn_s_setprio(0);
        asm volatile("s_waitcnt vmcnt(0)" ::: "memory");
        SCHEDB(); BAR(); SCHEDB();
    }
    // ---- tail: K-tile 7 (dbuf 1), fully staged & drained; no barriers ----
    BFRAGS(1);
    AFRAGS(1, 0); MFMAQ(0);
    AFRAGS(1, 1); MFMAQ(1);
    AFRAGS(1, 2); MFMAQ(2);
    AFRAGS(1, 3); MFMAQ(3);
    __syncthreads();   // seal K-loop before LDS reuse

    // --- epilogue: tanh(acc + proj1[b,d]) * v[d], partial-reduce over d ---
    float p1v[4], vv[4];
    #pragma unroll
    for (int ni = 0; ni < 4; ++ni) {
        int d = cb * 256 + wc * 64 + ni * 16 + llo;
        p1v[ni] = wsP1[b * 512 + d];
        vv[ni]  = vvec[d];
    }
    float part[32];
    #pragma unroll
    for (int mi = 0; mi < 8; ++mi)
        #pragma unroll
        for (int r = 0; r < 4; ++r) {
            float s = 0.f;
            #pragma unroll
            for (int ni = 0; ni < 4; ++ni)
                s += tanh_fast(acc[mi][ni][r] + p1v[ni]) * vv[ni];
            part[mi * 4 + r] = s;
        }
    // reduce across the 16-lane column group (lane bits 0..3)
    #pragma unroll
    for (int off = 1; off < 16; off <<= 1)
        #pragma unroll
        for (int i = 0; i < 32; ++i)
            part[i] += __shfl_xor(part[i], off, 64);

    float* red = (float*)lds;   // [4 wc][256 rows]; K-loop sealed
    if (llo == 0) {
        #pragma unroll
        for (int mi = 0; mi < 8; ++mi)
            #pragma unroll
            for (int r = 0; r < 4; ++r)
                red[wc * 256 + wr * 128 + mi * 16 + lhi * 4 + r] = part[mi * 4 + r];
    }
    __syncthreads();
    if (tid < 256) {
        float s = red[tid] + red[256 + tid] + red[512 + tid] + red[768 + tid];
        (cb ? wsS1 : out)[m0 + tid] = s;
    }
}

// ---------------------------------------------------------------------------
// Kernel 3: add the two column-half partials, row softmax over S=4096,
// write to out. 32 blocks x 256.
// ---------------------------------------------------------------------------
__global__ __launch_bounds__(256) void softmax_kernel(
    float* __restrict__ out, const float* __restrict__ wsS1) {
    __shared__ float wred[8];
    const int b = blockIdx.x, tid = threadIdx.x;
    float* row = out + (size_t)b * 4096;
    const float* row1 = wsS1 + (size_t)b * 4096;
    float vals[16];
    float lmax = -1e30f;
    #pragma unroll
    for (int i = 0; i < 16; ++i) {
        vals[i] = row[i * 256 + tid] + row1[i * 256 + tid];
        lmax = fmaxf(lmax, vals[i]);
    }
    #pragma unroll
    for (int off = 32; off >= 1; off >>= 1)
        lmax = fmaxf(lmax, __shfl_xor(lmax, off, 64));
    if ((tid & 63) == 0) wred[tid >> 6] = lmax;
    __syncthreads();
    float gmax = fmaxf(fmaxf(wred[0], wred[1]), fmaxf(wred[2], wred[3]));
    float lsum = 0.f;
    #pragma unroll
    for (int i = 0; i < 16; ++i) {
        vals[i] = expf(vals[i] - gmax);
        lsum += vals[i];
    }
    #pragma unroll
    for (int off = 32; off >= 1; off >>= 1)
        lsum += __shfl_xor(lsum, off, 64);
    if ((tid & 63) == 0) wred[4 + (tid >> 6)] = lsum;
    __syncthreads();
    float inv = 1.f / (wred[4] + wred[5] + wred[6] + wred[7]);
    #pragma unroll
    for (int i = 0; i < 16; ++i)
        row[i * 256 + tid] = vals[i] * inv;
}

extern "C" void kernel_launch(void* const* d_in, const int* in_sizes, int n_in,
                              void* d_out, int out_size, void* d_ws, size_t ws_size,
                              hipStream_t stream) {
    const float* dh   = (const float*)d_in[0];   // (32, 512)
    const float* enc  = (const float*)d_in[1];   // (32, 4096, 512)
    const float* Wat  = (const float*)d_in[2];   // (512, 1024)
    const float* batt = (const float*)d_in[3];   // (512,)
    const float* vvec = (const float*)d_in[4];   // (512,)
    float* out = (float*)d_out;                  // (32, 4096)

    unsigned short* wsB = (unsigned short*)d_ws;               // 512 KB bf16 W_e
    float* wsP1 = (float*)((char*)d_ws + 524288);              // 64 KB proj1
    float* wsS1 = (float*)((char*)d_ws + 589824);              // 512 KB partial

    hipLaunchKernelGGL(prep_kernel, dim3(96), dim3(512), 0, stream,
                       dh, Wat, batt, wsB, wsP1);
    hipLaunchKernelGGL(fused_kernel, dim3(1024), dim3(512), 0, stream,
                       enc, wsB, wsP1, vvec, out, wsS1);
    hipLaunchKernelGGL(softmax_kernel, dim3(32), dim3(256), 0, stream, out, wsS1);
}